// Round 1
// baseline (715.399 us; speedup 1.0000x reference)
//
#include <hip/hip_runtime.h>
#include <hip/hip_bf16.h>
#include <stdint.h>

typedef __attribute__((ext_vector_type(4))) float f32x4;
typedef __attribute__((ext_vector_type(8))) short bf16x8;

#define AS1 __attribute__((address_space(1)))
#define AS3 __attribute__((address_space(3)))

static __device__ __forceinline__ unsigned short f2bf(float f) {
  union { float f; unsigned u; } v; v.f = f;
  unsigned r = v.u + 0x7fffu + ((v.u >> 16) & 1u);
  return (unsigned short)(r >> 16);
}

// ---------------- fp32 -> bf16 conversion (vectorized) ----------------
__global__ __launch_bounds__(256) void conv_f32_bf16(const float* __restrict__ src,
                                                     unsigned short* __restrict__ dst,
                                                     int n) {
  int stride = gridDim.x * 256 * 8;
  for (int base = (blockIdx.x * 256 + threadIdx.x) * 8; base < n; base += stride) {
    float4 x0 = *(const float4*)(src + base);
    float4 x1 = *(const float4*)(src + base + 4);
    ushort4 o0, o1;
    o0.x = f2bf(x0.x); o0.y = f2bf(x0.y); o0.z = f2bf(x0.z); o0.w = f2bf(x0.w);
    o1.x = f2bf(x1.x); o1.y = f2bf(x1.y); o1.z = f2bf(x1.z); o1.w = f2bf(x1.w);
    *(ushort4*)(dst + base) = o0;
    *(ushort4*)(dst + base + 4) = o1;
  }
}

// ---------------- projection GEMM: X[8192,1024] @ W[1024,1024]^T + b ----------------
// 128x128 tile, BK=32, 4 waves (2x2), global_load_lds staging (m97 structure).
// Epilogue scatters into head-split layout:
//   transpose_v==0: dst[((b*16+h)*2048 + s)*64 + dh]   (Q, K)
//   transpose_v==1: dst[((b*16+h)*64 + dh)*2048 + s]   (V transposed for PV B-frags)
__global__ __launch_bounds__(256) void proj_gemm(const unsigned short* __restrict__ A,
                                                 const unsigned short* __restrict__ W,
                                                 const float* __restrict__ bias,
                                                 unsigned short* __restrict__ dst,
                                                 int transpose_v) {
  const int K = 1024, S = 2048, H = 16;
  __shared__ unsigned short As[128 * 32];
  __shared__ unsigned short Bs[128 * 32];
  const int tid = threadIdx.x;
  const int l = tid & 63;
  const int w = tid >> 6;
  const int m0 = blockIdx.x * 128, n0 = blockIdx.y * 128;
  const int wm = w >> 1, wn = w & 1;

  f32x4 acc[4][4] = {};

  // staging geometry: slot = w*2+i covers 16 rows; lane covers 16B (8 bf16)
  const int srow = (l >> 2);        // 0..15 within slot
  const int skc = (l & 3) * 8;      // k offset 0,8,16,24

  for (int k0 = 0; k0 < K; k0 += 32) {
#pragma unroll
    for (int i = 0; i < 2; ++i) {
      int slot = w * 2 + i;
      int row = slot * 16 + srow;
      const unsigned short* ga = A + (long)(m0 + row) * K + k0 + skc;
      const unsigned short* gb = W + (long)(n0 + row) * K + k0 + skc;
      __builtin_amdgcn_global_load_lds((const AS1 unsigned int*)ga,
                                       (AS3 unsigned int*)(As + slot * 512 + l * 8),
                                       16, 0, 0);
      __builtin_amdgcn_global_load_lds((const AS1 unsigned int*)gb,
                                       (AS3 unsigned int*)(Bs + slot * 512 + l * 8),
                                       16, 0, 0);
    }
    __syncthreads();  // drains vmcnt + barrier

    bf16x8 af[4], bfr[4];
    const int kc = (l >> 4) * 8;
#pragma unroll
    for (int mi = 0; mi < 4; ++mi)
      af[mi] = *(const bf16x8*)&As[(wm * 64 + mi * 16 + (l & 15)) * 32 + kc];
#pragma unroll
    for (int ni = 0; ni < 4; ++ni)
      bfr[ni] = *(const bf16x8*)&Bs[(wn * 64 + ni * 16 + (l & 15)) * 32 + kc];
#pragma unroll
    for (int mi = 0; mi < 4; ++mi)
#pragma unroll
      for (int ni = 0; ni < 4; ++ni)
        acc[mi][ni] = __builtin_amdgcn_mfma_f32_16x16x32_bf16(af[mi], bfr[ni], acc[mi][ni], 0, 0, 0);
    __syncthreads();
  }

  // epilogue: bias + bf16 + head-split scatter. C layout: col=l&15, row=(l>>4)*4+r
#pragma unroll
  for (int ni = 0; ni < 4; ++ni) {
    int col = n0 + wn * 64 + ni * 16 + (l & 15);
    float bv = bias[col];
    int h = col >> 6, dh = col & 63;
#pragma unroll
    for (int mi = 0; mi < 4; ++mi) {
#pragma unroll
      for (int r = 0; r < 4; ++r) {
        int m = m0 + wm * 64 + mi * 16 + (l >> 4) * 4 + r;
        int b = m >> 11, s = m & 2047;
        unsigned short obf = f2bf(acc[mi][ni][r] + bv);
        long addr;
        if (!transpose_v)
          addr = ((long)(b * H + h) * S + s) * 64 + dh;
        else
          addr = ((long)(b * H + h) * 64 + dh) * S + s;
        dst[addr] = obf;
      }
    }
  }
}

// ---------------- flash attention ----------------
// grid: (S/64, B*H); 256 threads = 4 waves, 16 q-rows per wave, KV tile 32.
__global__ __launch_bounds__(256) void attn_kernel(const unsigned short* __restrict__ qh,
                                                   const unsigned short* __restrict__ kh,
                                                   const unsigned short* __restrict__ vt,
                                                   const float* __restrict__ mask,
                                                   float* __restrict__ out) {
  const int S = 2048;
  const int bh = blockIdx.y;
  const int b = bh >> 4, h = bh & 15;
  const int tid = threadIdx.x, l = tid & 63, w = tid >> 6;
  const unsigned short* qb = qh + (long)bh * S * 64;
  const unsigned short* kb = kh + (long)bh * S * 64;
  const unsigned short* vb = vt + (long)bh * 64 * S;

  __shared__ float smask[2048];
  __shared__ unsigned short pbuf[4][16 * 40];  // per-wave P staging, pitch 40 (80B, 16B-aligned)
  for (int i = tid; i < S; i += 256) smask[i] = -10000.0f * (1.0f - mask[b * S + i]);
  __syncthreads();

  const int q0 = blockIdx.x * 64 + w * 16;
  const int kc = (l >> 4) * 8;
  bf16x8 qf0, qf1;
  {
    int row = q0 + (l & 15);
    qf0 = *(const bf16x8*)&qb[row * 64 + kc];
    qf1 = *(const bf16x8*)&qb[row * 64 + kc + 32];
  }

  f32x4 acco[4] = {};
  float mrow[4], lrow[4];
#pragma unroll
  for (int r = 0; r < 4; ++r) { mrow[r] = -1e30f; lrow[r] = 0.0f; }
  unsigned short* pw = pbuf[w];

  for (int kv0 = 0; kv0 < S; kv0 += 32) {
    // ---- QK^T: 16x32 score tile per wave ----
    f32x4 s0 = {0.f, 0.f, 0.f, 0.f}, s1 = {0.f, 0.f, 0.f, 0.f};
    const unsigned short* kp0 = &kb[(kv0 + (l & 15)) * 64 + kc];
    const unsigned short* kp1 = &kb[(kv0 + 16 + (l & 15)) * 64 + kc];
    s0 = __builtin_amdgcn_mfma_f32_16x16x32_bf16(qf0, *(const bf16x8*)kp0, s0, 0, 0, 0);
    s0 = __builtin_amdgcn_mfma_f32_16x16x32_bf16(qf1, *(const bf16x8*)(kp0 + 32), s0, 0, 0, 0);
    s1 = __builtin_amdgcn_mfma_f32_16x16x32_bf16(qf0, *(const bf16x8*)kp1, s1, 0, 0, 0);
    s1 = __builtin_amdgcn_mfma_f32_16x16x32_bf16(qf1, *(const bf16x8*)(kp1 + 32), s1, 0, 0, 0);

    float madd0 = smask[kv0 + (l & 15)];
    float madd1 = smask[kv0 + 16 + (l & 15)];
    float sc0[4], sc1[4], scalef[4], p0[4], p1[4];
#pragma unroll
    for (int r = 0; r < 4; ++r) {
      sc0[r] = s0[r] * 0.125f + madd0;
      sc1[r] = s1[r] * 0.125f + madd1;
    }
    // ---- online softmax (row = (l>>4)*4+r, 32 cols spread over 16 lanes x 2) ----
#pragma unroll
    for (int r = 0; r < 4; ++r) {
      float t = fmaxf(sc0[r], sc1[r]);
      t = fmaxf(t, __shfl_xor(t, 1, 16));
      t = fmaxf(t, __shfl_xor(t, 2, 16));
      t = fmaxf(t, __shfl_xor(t, 4, 16));
      t = fmaxf(t, __shfl_xor(t, 8, 16));
      float mn = fmaxf(mrow[r], t);
      scalef[r] = __expf(mrow[r] - mn);
      mrow[r] = mn;
      p0[r] = __expf(sc0[r] - mn);
      p1[r] = __expf(sc1[r] - mn);
      float ps = p0[r] + p1[r];
      ps += __shfl_xor(ps, 1, 16);
      ps += __shfl_xor(ps, 2, 16);
      ps += __shfl_xor(ps, 4, 16);
      ps += __shfl_xor(ps, 8, 16);
      lrow[r] = lrow[r] * scalef[r] + ps;
    }
#pragma unroll
    for (int nt = 0; nt < 4; ++nt)
#pragma unroll
      for (int r = 0; r < 4; ++r) acco[nt][r] *= scalef[r];

    // ---- P -> LDS (bf16), per-wave private buffer ----
#pragma unroll
    for (int r = 0; r < 4; ++r) {
      int prow = (l >> 4) * 4 + r;
      pw[prow * 40 + (l & 15)] = f2bf(p0[r]);
      pw[prow * 40 + 16 + (l & 15)] = f2bf(p1[r]);
    }
    asm volatile("s_waitcnt lgkmcnt(0)" ::: "memory");

    // ---- PV: A-frag from LDS, B-frags from V^T global (L2-resident) ----
    bf16x8 ap = *(const bf16x8*)&pw[(l & 15) * 40 + kc];
#pragma unroll
    for (int nt = 0; nt < 4; ++nt) {
      const unsigned short* vp = &vb[(nt * 16 + (l & 15)) * S + kv0 + kc];
      acco[nt] = __builtin_amdgcn_mfma_f32_16x16x32_bf16(ap, *(const bf16x8*)vp, acco[nt], 0, 0, 0);
    }
    asm volatile("s_waitcnt lgkmcnt(0)" ::: "memory");  // ap consumed before next-iter writes
  }

  // ---- epilogue: divide by l, write fp32 merged-head output ----
#pragma unroll
  for (int nt = 0; nt < 4; ++nt) {
    int d = h * 64 + nt * 16 + (l & 15);
#pragma unroll
    for (int r = 0; r < 4; ++r) {
      int qg = q0 + (l >> 4) * 4 + r;
      out[((long)(b * S + qg)) * 1024 + d] = acco[nt][r] / lrow[r];
    }
  }
}

// ---------------- launch ----------------
extern "C" void kernel_launch(void* const* d_in, const int* in_sizes, int n_in,
                              void* d_out, int out_size, void* d_ws, size_t ws_size,
                              hipStream_t stream) {
  const float* q  = (const float*)d_in[0];
  const float* k  = (const float*)d_in[1];
  const float* v  = (const float*)d_in[2];
  const float* mask = (const float*)d_in[3];
  const float* wq = (const float*)d_in[4];
  const float* bq = (const float*)d_in[5];
  const float* wk = (const float*)d_in[6];
  const float* bk = (const float*)d_in[7];
  const float* wv = (const float*)d_in[8];
  const float* bv = (const float*)d_in[9];
  float* out = (float*)d_out;

  const int NX = 4 * 2048 * 1024;  // 8388608 elems per activation tensor
  const int NW = 1024 * 1024;      // weight elems

  char* ws = (char*)d_ws;
  unsigned short* Xq = (unsigned short*)(ws);
  unsigned short* Xk = (unsigned short*)(ws + 16777216L);
  unsigned short* Xv = (unsigned short*)(ws + 33554432L);
  unsigned short* Wq = (unsigned short*)(ws + 50331648L);
  unsigned short* Wk = (unsigned short*)(ws + 52428800L);
  unsigned short* Wv = (unsigned short*)(ws + 54525952L);
  unsigned short* Qh = (unsigned short*)(ws + 56623104L);
  unsigned short* Kh = (unsigned short*)(ws + 73400320L);
  unsigned short* Vt = (unsigned short*)(ws + 90177536L);

  // 1) convert inputs/weights to bf16
  conv_f32_bf16<<<NX / 2048, 256, 0, stream>>>(q, Xq, NX);
  conv_f32_bf16<<<NX / 2048, 256, 0, stream>>>(k, Xk, NX);
  conv_f32_bf16<<<NX / 2048, 256, 0, stream>>>(v, Xv, NX);
  conv_f32_bf16<<<NW / 2048, 256, 0, stream>>>(wq, Wq, NW);
  conv_f32_bf16<<<NW / 2048, 256, 0, stream>>>(wk, Wk, NW);
  conv_f32_bf16<<<NW / 2048, 256, 0, stream>>>(wv, Wv, NW);

  // 2) QKV projections with head-split epilogue
  dim3 ggrid(64, 8);
  proj_gemm<<<ggrid, 256, 0, stream>>>(Xq, Wq, bq, Qh, 0);
  proj_gemm<<<ggrid, 256, 0, stream>>>(Xk, Wk, bk, Kh, 0);
  proj_gemm<<<ggrid, 256, 0, stream>>>(Xv, Wv, bv, Vt, 1);

  // 3) flash attention + head merge
  dim3 agrid(32, 64);
  attn_kernel<<<agrid, 256, 0, stream>>>(Qh, Kh, Vt, mask, out);
}

// Round 2
// 488.542 us; speedup vs baseline: 1.4644x; 1.4644x over previous
//
#include <hip/hip_runtime.h>
#include <hip/hip_bf16.h>
#include <stdint.h>

typedef __attribute__((ext_vector_type(4))) float f32x4;
typedef __attribute__((ext_vector_type(16))) float f32x16;
typedef __attribute__((ext_vector_type(8))) short bf16x8;

#define AS1 __attribute__((address_space(1)))
#define AS3 __attribute__((address_space(3)))

#if defined(__has_builtin)
#if __has_builtin(__builtin_amdgcn_exp2f)
#define EXPF(x) __builtin_amdgcn_exp2f(x)
#define UNITS 1.4426950408889634f
#endif
#endif
#ifndef EXPF
#define EXPF(x) __expf(x)
#define UNITS 1.0f
#endif

static __device__ __forceinline__ unsigned short f2bf(float f) {
  union { float f; unsigned u; } v; v.f = f;
  unsigned r = v.u + 0x7fffu + ((v.u >> 16) & 1u);
  return (unsigned short)(r >> 16);
}

static __device__ __forceinline__ unsigned pkbf(float lo, float hi) {
  __hip_bfloat162 h2 = __float22bfloat162_rn(make_float2(lo, hi));
  union { __hip_bfloat162 h; unsigned u; } c; c.h = h2; return c.u;
}

// ---------------- fp32 -> bf16 conversion (vectorized) ----------------
__global__ __launch_bounds__(256) void conv_f32_bf16(const float* __restrict__ src,
                                                     unsigned short* __restrict__ dst,
                                                     int n) {
  int stride = gridDim.x * 256 * 8;
  for (int base = (blockIdx.x * 256 + threadIdx.x) * 8; base < n; base += stride) {
    float4 x0 = *(const float4*)(src + base);
    float4 x1 = *(const float4*)(src + base + 4);
    ushort4 o0, o1;
    o0.x = f2bf(x0.x); o0.y = f2bf(x0.y); o0.z = f2bf(x0.z); o0.w = f2bf(x0.w);
    o1.x = f2bf(x1.x); o1.y = f2bf(x1.y); o1.z = f2bf(x1.z); o1.w = f2bf(x1.w);
    *(ushort4*)(dst + base) = o0;
    *(ushort4*)(dst + base + 4) = o1;
  }
}

// ---------------- projection GEMM (unchanged from round 0) ----------------
__global__ __launch_bounds__(256) void proj_gemm(const unsigned short* __restrict__ A,
                                                 const unsigned short* __restrict__ W,
                                                 const float* __restrict__ bias,
                                                 unsigned short* __restrict__ dst,
                                                 int transpose_v) {
  const int K = 1024, S = 2048, H = 16;
  __shared__ unsigned short As[128 * 32];
  __shared__ unsigned short Bs[128 * 32];
  const int tid = threadIdx.x;
  const int l = tid & 63;
  const int w = tid >> 6;
  const int m0 = blockIdx.x * 128, n0 = blockIdx.y * 128;
  const int wm = w >> 1, wn = w & 1;

  f32x4 acc[4][4] = {};

  const int srow = (l >> 2);
  const int skc = (l & 3) * 8;

  for (int k0 = 0; k0 < K; k0 += 32) {
#pragma unroll
    for (int i = 0; i < 2; ++i) {
      int slot = w * 2 + i;
      int row = slot * 16 + srow;
      const unsigned short* ga = A + (long)(m0 + row) * K + k0 + skc;
      const unsigned short* gb = W + (long)(n0 + row) * K + k0 + skc;
      __builtin_amdgcn_global_load_lds((const AS1 unsigned int*)ga,
                                       (AS3 unsigned int*)(As + slot * 512 + l * 8),
                                       16, 0, 0);
      __builtin_amdgcn_global_load_lds((const AS1 unsigned int*)gb,
                                       (AS3 unsigned int*)(Bs + slot * 512 + l * 8),
                                       16, 0, 0);
    }
    __syncthreads();

    bf16x8 af[4], bfr[4];
    const int kc = (l >> 4) * 8;
#pragma unroll
    for (int mi = 0; mi < 4; ++mi)
      af[mi] = *(const bf16x8*)&As[(wm * 64 + mi * 16 + (l & 15)) * 32 + kc];
#pragma unroll
    for (int ni = 0; ni < 4; ++ni)
      bfr[ni] = *(const bf16x8*)&Bs[(wn * 64 + ni * 16 + (l & 15)) * 32 + kc];
#pragma unroll
    for (int mi = 0; mi < 4; ++mi)
#pragma unroll
      for (int ni = 0; ni < 4; ++ni)
        acc[mi][ni] = __builtin_amdgcn_mfma_f32_16x16x32_bf16(af[mi], bfr[ni], acc[mi][ni], 0, 0, 0);
    __syncthreads();
  }

#pragma unroll
  for (int ni = 0; ni < 4; ++ni) {
    int col = n0 + wn * 64 + ni * 16 + (l & 15);
    float bv = bias[col];
    int h = col >> 6, dh = col & 63;
#pragma unroll
    for (int mi = 0; mi < 4; ++mi) {
#pragma unroll
      for (int r = 0; r < 4; ++r) {
        int m = m0 + wm * 64 + mi * 16 + (l >> 4) * 4 + r;
        int b = m >> 11, s = m & 2047;
        unsigned short obf = f2bf(acc[mi][ni][r] + bv);
        long addr;
        if (!transpose_v)
          addr = ((long)(b * H + h) * S + s) * 64 + dh;
        else
          addr = ((long)(b * H + h) * 64 + dh) * S + s;
        dst[addr] = obf;
      }
    }
  }
}

// ---------------- flash attention: 8 waves x 32 q-rows, KVBLK=64, 32x32 MFMA ----------------
// Swapped QK^T (mfma(K,Q)) -> S^T in regs: lane l holds, for q-row (l&31),
// k-rows (r&3)+8*(r>>2)+4*(l>>5) of each 32-k subtile. In-register softmax,
// P->bf16 via packed cvt + v_permlane32_swap, PV as mfma(V^T, P^T) -> O^T.
__global__ __launch_bounds__(512, 2) void attn_kernel(const unsigned short* __restrict__ qh,
                                                      const unsigned short* __restrict__ kh,
                                                      const unsigned short* __restrict__ vt,
                                                      const float* __restrict__ mask,
                                                      float* __restrict__ out) {
  const int S = 2048;
  // XCD swizzle: all 8 q-blocks of one bh land on the same XCD (K/V L2-resident).
  int bid = blockIdx.x;
  int xcd = bid & 7, jj = bid >> 3;
  int bh = xcd * 8 + (jj & 7);
  int qblk = jj >> 3;
  int b = bh >> 4, h = bh & 15;
  int tid = threadIdx.x, l = tid & 63, w = tid >> 6;
  int hi = l >> 5, qc = l & 31;

  const unsigned short* qb = qh + (long)bh * S * 64;
  const unsigned short* kb = kh + (long)bh * S * 64;
  const unsigned short* vb = vt + (long)bh * 64 * S;

  __shared__ float smask[2048];
  __shared__ float olds[8][16][65];  // per-wave epilogue transpose (2 passes of 16 q-rows)
  for (int i = tid; i < S; i += 512)
    smask[i] = (-10000.0f * UNITS) * (1.0f - mask[b * S + i]);
  __syncthreads();

  const int q0 = qblk * 256 + w * 32;

  // Q as B-fragments: B[k=d][n=q]; lane: n=qc, k=8*hi+j within each d-chunk of 16
  bf16x8 qf[4];
#pragma unroll
  for (int dc = 0; dc < 4; ++dc)
    qf[dc] = *(const bf16x8*)&qb[(q0 + qc) * 64 + dc * 16 + 8 * hi];

  f32x16 acco[2] = {};               // O^T accum: [d-tile][16 regs]; col=q, row=d pattern
  float m_run = -1e30f, lrow = 0.0f;
  const float kSc = 0.125f * UNITS;  // 1/sqrt(64) (in exp2 units if available)
  const float THR = 8.0f * UNITS;

  for (int kv0 = 0; kv0 < S; kv0 += 64) {
    // ---- issue all K and V fragment loads for this tile up front ----
    bf16x8 kf[2][4], vfr[2][4];
#pragma unroll
    for (int ks = 0; ks < 2; ++ks)
#pragma unroll
      for (int dc = 0; dc < 4; ++dc)
        kf[ks][dc] = *(const bf16x8*)&kb[(kv0 + ks * 32 + qc) * 64 + dc * 16 + 8 * hi];
#pragma unroll
    for (int dt = 0; dt < 2; ++dt)
#pragma unroll
      for (int c2 = 0; c2 < 4; ++c2)
        vfr[dt][c2] = *(const bf16x8*)&vb[(dt * 32 + qc) * S + kv0 + c2 * 16 + 8 * hi];

    // ---- QK^T (swapped): S^T[k][q] ----
    f32x16 st0 = {}, st1 = {};
    __builtin_amdgcn_s_setprio(1);
#pragma unroll
    for (int dc = 0; dc < 4; ++dc) {
      st0 = __builtin_amdgcn_mfma_f32_32x32x16_bf16(kf[0][dc], qf[dc], st0, 0, 0, 0);
      st1 = __builtin_amdgcn_mfma_f32_32x32x16_bf16(kf[1][dc], qf[dc], st1, 0, 0, 0);
    }
    __builtin_amdgcn_s_setprio(0);

    // ---- scores + mask (mask via float4 LDS broadcast; krow=(r&3)+8*(r>>2)+4*hi) ----
    float mf[2][16];
#pragma unroll
    for (int ks = 0; ks < 2; ++ks)
#pragma unroll
      for (int g = 0; g < 4; ++g) {
        float4 t = *(const float4*)&smask[kv0 + ks * 32 + 4 * hi + g * 8];
        mf[ks][g * 4 + 0] = t.x; mf[ks][g * 4 + 1] = t.y;
        mf[ks][g * 4 + 2] = t.z; mf[ks][g * 4 + 3] = t.w;
      }
    float p[2][16];
#pragma unroll
    for (int r = 0; r < 16; ++r) {
      p[0][r] = fmaf(st0[r], kSc, mf[0][r]);
      p[1][r] = fmaf(st1[r], kSc, mf[1][r]);
    }

    // ---- tile max (4 independent chains + cross-half) ----
    float a0 = p[0][0], a1 = p[0][1], a2 = p[0][2], a3 = p[0][3];
#pragma unroll
    for (int r = 4; r < 16; r += 4) {
      a0 = fmaxf(a0, p[0][r]); a1 = fmaxf(a1, p[0][r + 1]);
      a2 = fmaxf(a2, p[0][r + 2]); a3 = fmaxf(a3, p[0][r + 3]);
    }
#pragma unroll
    for (int r = 0; r < 16; r += 4) {
      a0 = fmaxf(a0, p[1][r]); a1 = fmaxf(a1, p[1][r + 1]);
      a2 = fmaxf(a2, p[1][r + 2]); a3 = fmaxf(a3, p[1][r + 3]);
    }
    float pm = fmaxf(fmaxf(a0, a1), fmaxf(a2, a3));
    pm = fmaxf(pm, __shfl_xor(pm, 32));

    // ---- defer-max (T13) ----
    if (!__all(pm <= m_run + THR)) {
      float mnew = fmaxf(m_run, pm);
      float scl = EXPF(m_run - mnew);
      lrow *= scl;
#pragma unroll
      for (int dt = 0; dt < 2; ++dt)
#pragma unroll
        for (int r = 0; r < 16; ++r) acco[dt][r] *= scl;
      m_run = mnew;
    }

    // ---- exp + row-sum (4 chains) ----
    float s0 = 0.f, s1 = 0.f, s2 = 0.f, s3 = 0.f;
#pragma unroll
    for (int ks = 0; ks < 2; ++ks)
#pragma unroll
      for (int r = 0; r < 16; r += 4) {
        p[ks][r]     = EXPF(p[ks][r] - m_run);     s0 += p[ks][r];
        p[ks][r + 1] = EXPF(p[ks][r + 1] - m_run); s1 += p[ks][r + 1];
        p[ks][r + 2] = EXPF(p[ks][r + 2] - m_run); s2 += p[ks][r + 2];
        p[ks][r + 3] = EXPF(p[ks][r + 3] - m_run); s3 += p[ks][r + 3];
      }
    float ps = (s0 + s1) + (s2 + s3);
    ps += __shfl_xor(ps, 32);
    lrow += ps;

    // ---- pack P->bf16 (T12: cvt_pk pairs + permlane32_swap), then PV ----
#pragma unroll
    for (int ks = 0; ks < 2; ++ks) {
      unsigned cp0 = pkbf(p[ks][0], p[ks][1]);
      unsigned cp1 = pkbf(p[ks][2], p[ks][3]);
      unsigned cp2 = pkbf(p[ks][4], p[ks][5]);
      unsigned cp3 = pkbf(p[ks][6], p[ks][7]);
      unsigned cp4 = pkbf(p[ks][8], p[ks][9]);
      unsigned cp5 = pkbf(p[ks][10], p[ks][11]);
      unsigned cp6 = pkbf(p[ks][12], p[ks][13]);
      unsigned cp7 = pkbf(p[ks][14], p[ks][15]);
      // after swap: op0 = {op0.lo-half, op1.lo-half}, op1 = {op0.hi-half, op1.hi-half}
      asm volatile("v_permlane32_swap_b32 %0, %1" : "+v"(cp0), "+v"(cp2));
      asm volatile("v_permlane32_swap_b32 %0, %1" : "+v"(cp1), "+v"(cp3));
      asm volatile("v_permlane32_swap_b32 %0, %1" : "+v"(cp4), "+v"(cp6));
      asm volatile("v_permlane32_swap_b32 %0, %1" : "+v"(cp5), "+v"(cp7));
      union { unsigned u[4]; bf16x8 v; } B0, B1;
      B0.u[0] = cp0; B0.u[1] = cp1; B0.u[2] = cp2; B0.u[3] = cp3;
      B1.u[0] = cp4; B1.u[1] = cp5; B1.u[2] = cp6; B1.u[3] = cp7;
      __builtin_amdgcn_s_setprio(1);
      acco[0] = __builtin_amdgcn_mfma_f32_32x32x16_bf16(vfr[0][ks * 2 + 0], B0.v, acco[0], 0, 0, 0);
      acco[1] = __builtin_amdgcn_mfma_f32_32x32x16_bf16(vfr[1][ks * 2 + 0], B0.v, acco[1], 0, 0, 0);
      acco[0] = __builtin_amdgcn_mfma_f32_32x32x16_bf16(vfr[0][ks * 2 + 1], B1.v, acco[0], 0, 0, 0);
      acco[1] = __builtin_amdgcn_mfma_f32_32x32x16_bf16(vfr[1][ks * 2 + 1], B1.v, acco[1], 0, 0, 0);
      __builtin_amdgcn_s_setprio(0);
    }
  }

  // ---- epilogue: normalize, per-wave LDS transpose, coalesced fp32 stores ----
  float linv = 1.0f / lrow;
#pragma unroll
  for (int pass = 0; pass < 2; ++pass) {
    if ((qc >> 4) == pass) {
#pragma unroll
      for (int dt = 0; dt < 2; ++dt)
#pragma unroll
        for (int r = 0; r < 16; ++r) {
          int d = dt * 32 + (r & 3) + 8 * (r >> 2) + 4 * hi;
          olds[w][qc & 15][d] = acco[dt][r] * linv;
        }
    }
    asm volatile("s_waitcnt lgkmcnt(0)" ::: "memory");
#pragma unroll
    for (int r = 0; r < 16; ++r) {
      float val = olds[w][r][l];
      out[((long)b * 2048 + q0 + pass * 16 + r) * 1024 + h * 64 + l] = val;
    }
    asm volatile("s_waitcnt lgkmcnt(0)" ::: "memory");
  }
}

// ---------------- launch ----------------
extern "C" void kernel_launch(void* const* d_in, const int* in_sizes, int n_in,
                              void* d_out, int out_size, void* d_ws, size_t ws_size,
                              hipStream_t stream) {
  const float* q  = (const float*)d_in[0];
  const float* k  = (const float*)d_in[1];
  const float* v  = (const float*)d_in[2];
  const float* mask = (const float*)d_in[3];
  const float* wq = (const float*)d_in[4];
  const float* bq = (const float*)d_in[5];
  const float* wk = (const float*)d_in[6];
  const float* bk = (const float*)d_in[7];
  const float* wv = (const float*)d_in[8];
  const float* bv = (const float*)d_in[9];
  float* out = (float*)d_out;

  const int NX = 4 * 2048 * 1024;
  const int NW = 1024 * 1024;

  char* ws = (char*)d_ws;
  unsigned short* Xq = (unsigned short*)(ws);
  unsigned short* Xk = (unsigned short*)(ws + 16777216L);
  unsigned short* Xv = (unsigned short*)(ws + 33554432L);
  unsigned short* Wq = (unsigned short*)(ws + 50331648L);
  unsigned short* Wk = (unsigned short*)(ws + 52428800L);
  unsigned short* Wv = (unsigned short*)(ws + 54525952L);
  unsigned short* Qh = (unsigned short*)(ws + 56623104L);
  unsigned short* Kh = (unsigned short*)(ws + 73400320L);
  unsigned short* Vt = (unsigned short*)(ws + 90177536L);

  conv_f32_bf16<<<NX / 2048, 256, 0, stream>>>(q, Xq, NX);
  conv_f32_bf16<<<NX / 2048, 256, 0, stream>>>(k, Xk, NX);
  conv_f32_bf16<<<NX / 2048, 256, 0, stream>>>(v, Xv, NX);
  conv_f32_bf16<<<NW / 2048, 256, 0, stream>>>(wq, Wq, NW);
  conv_f32_bf16<<<NW / 2048, 256, 0, stream>>>(wk, Wk, NW);
  conv_f32_bf16<<<NW / 2048, 256, 0, stream>>>(wv, Wv, NW);

  dim3 ggrid(64, 8);
  proj_gemm<<<ggrid, 256, 0, stream>>>(Xq, Wq, bq, Qh, 0);
  proj_gemm<<<ggrid, 256, 0, stream>>>(Xk, Wk, bk, Kh, 0);
  proj_gemm<<<ggrid, 256, 0, stream>>>(Xv, Wv, bv, Vt, 1);

  attn_kernel<<<512, 512, 0, stream>>>(Qh, Kh, Vt, mask, out);
}

// Round 4
// 481.283 us; speedup vs baseline: 1.4864x; 1.0151x over previous
//
#include <hip/hip_runtime.h>
#include <hip/hip_bf16.h>
#include <stdint.h>

typedef __attribute__((ext_vector_type(4))) float f32x4;
typedef __attribute__((ext_vector_type(16))) float f32x16;
typedef __attribute__((ext_vector_type(8))) short bf16x8;

#define AS1 __attribute__((address_space(1)))
#define AS3 __attribute__((address_space(3)))

#if defined(__has_builtin)
#if __has_builtin(__builtin_amdgcn_exp2f)
#define EXPF(x) __builtin_amdgcn_exp2f(x)
#define UNITS 1.4426950408889634f
#endif
#endif
#ifndef EXPF
#define EXPF(x) __expf(x)
#define UNITS 1.0f
#endif

static __device__ __forceinline__ unsigned short f2bf(float f) {
  union { float f; unsigned u; } v; v.f = f;
  unsigned r = v.u + 0x7fffu + ((v.u >> 16) & 1u);
  return (unsigned short)(r >> 16);
}

static __device__ __forceinline__ unsigned pkbf(float lo, float hi) {
  __hip_bfloat162 h2 = __float22bfloat162_rn(make_float2(lo, hi));
  union { __hip_bfloat162 h; unsigned u; } c; c.h = h2; return c.u;
}

// ---------------- fused fp32 -> bf16 conversion for all 6 tensors ----------------
// q,k,v: 4096 blocks each (8.39M elems); wq,wk,wv: 512 blocks each (1.05M elems).
__global__ __launch_bounds__(256) void conv_all(
    const float* __restrict__ q, const float* __restrict__ k, const float* __restrict__ v,
    const float* __restrict__ wq, const float* __restrict__ wk, const float* __restrict__ wv,
    unsigned short* __restrict__ Xq, unsigned short* __restrict__ Xk, unsigned short* __restrict__ Xv,
    unsigned short* __restrict__ Wq, unsigned short* __restrict__ Wk, unsigned short* __restrict__ Wv) {
  int bid = blockIdx.x;
  const float* src; unsigned short* dst; int base;
  if (bid < 12288) {
    int t = bid >> 12;
    base = (bid & 4095) * 2048;
    if (t == 0) { src = q; dst = Xq; }
    else if (t == 1) { src = k; dst = Xk; }
    else { src = v; dst = Xv; }
  } else {
    int r = bid - 12288;
    int t = r >> 9;
    base = (r & 511) * 2048;
    if (t == 0) { src = wq; dst = Wq; }
    else if (t == 1) { src = wk; dst = Wk; }
    else { src = wv; dst = Wv; }
  }
  int i = base + threadIdx.x * 8;
  float4 x0 = *(const float4*)(src + i);
  float4 x1 = *(const float4*)(src + i + 4);
  ushort4 o0, o1;
  o0.x = f2bf(x0.x); o0.y = f2bf(x0.y); o0.z = f2bf(x0.z); o0.w = f2bf(x0.w);
  o1.x = f2bf(x1.x); o1.y = f2bf(x1.y); o1.z = f2bf(x1.z); o1.w = f2bf(x1.w);
  *(ushort4*)(dst + i) = o0;
  *(ushort4*)(dst + i + 4) = o1;
}

// ---------------- merged QKV projection GEMM (z selects q/k/v) ----------------
__global__ __launch_bounds__(256) void proj_gemm3(
    const unsigned short* __restrict__ Xq, const unsigned short* __restrict__ Xk,
    const unsigned short* __restrict__ Xv,
    const unsigned short* __restrict__ Wqp, const unsigned short* __restrict__ Wkp,
    const unsigned short* __restrict__ Wvp,
    const float* __restrict__ bq, const float* __restrict__ bk, const float* __restrict__ bv,
    unsigned short* __restrict__ Qh, unsigned short* __restrict__ Kh,
    unsigned short* __restrict__ Vt) {
  const int K = 1024, S = 2048, H = 16;
  int z = blockIdx.z;
  const unsigned short *A, *W; const float* bias; unsigned short* dst; int transpose_v;
  if (z == 0)      { A = Xq; W = Wqp; bias = bq; dst = Qh; transpose_v = 0; }
  else if (z == 1) { A = Xk; W = Wkp; bias = bk; dst = Kh; transpose_v = 0; }
  else             { A = Xv; W = Wvp; bias = bv; dst = Vt; transpose_v = 1; }

  __shared__ unsigned short As[128 * 32];
  __shared__ unsigned short Bs[128 * 32];
  const int tid = threadIdx.x;
  const int l = tid & 63;
  const int w = tid >> 6;
  const int m0 = blockIdx.x * 128, n0 = blockIdx.y * 128;
  const int wm = w >> 1, wn = w & 1;

  f32x4 acc[4][4] = {};

  const int srow = (l >> 2);
  const int skc = (l & 3) * 8;

  for (int k0 = 0; k0 < K; k0 += 32) {
#pragma unroll
    for (int i = 0; i < 2; ++i) {
      int slot = w * 2 + i;
      int row = slot * 16 + srow;
      const unsigned short* ga = A + (long)(m0 + row) * K + k0 + skc;
      const unsigned short* gb = W + (long)(n0 + row) * K + k0 + skc;
      __builtin_amdgcn_global_load_lds((const AS1 unsigned int*)ga,
                                       (AS3 unsigned int*)(As + slot * 512 + l * 8),
                                       16, 0, 0);
      __builtin_amdgcn_global_load_lds((const AS1 unsigned int*)gb,
                                       (AS3 unsigned int*)(Bs + slot * 512 + l * 8),
                                       16, 0, 0);
    }
    __syncthreads();

    bf16x8 af[4], bfr[4];
    const int kc = (l >> 4) * 8;
#pragma unroll
    for (int mi = 0; mi < 4; ++mi)
      af[mi] = *(const bf16x8*)&As[(wm * 64 + mi * 16 + (l & 15)) * 32 + kc];
#pragma unroll
    for (int ni = 0; ni < 4; ++ni)
      bfr[ni] = *(const bf16x8*)&Bs[(wn * 64 + ni * 16 + (l & 15)) * 32 + kc];
#pragma unroll
    for (int mi = 0; mi < 4; ++mi)
#pragma unroll
      for (int ni = 0; ni < 4; ++ni)
        acc[mi][ni] = __builtin_amdgcn_mfma_f32_16x16x32_bf16(af[mi], bfr[ni], acc[mi][ni], 0, 0, 0);
    __syncthreads();
  }

#pragma unroll
  for (int ni = 0; ni < 4; ++ni) {
    int col = n0 + wn * 64 + ni * 16 + (l & 15);
    float bv_ = bias[col];
    int h = col >> 6, dh = col & 63;
#pragma unroll
    for (int mi = 0; mi < 4; ++mi) {
#pragma unroll
      for (int r = 0; r < 4; ++r) {
        int m = m0 + wm * 64 + mi * 16 + (l >> 4) * 4 + r;
        int b = m >> 11, s = m & 2047;
        unsigned short obf = f2bf(acc[mi][ni][r] + bv_);
        long addr;
        if (!transpose_v)
          addr = ((long)(b * H + h) * S + s) * 64 + dh;
        else
          addr = ((long)(b * H + h) * 64 + dh) * S + s;
        dst[addr] = obf;
      }
    }
  }
}

// ---------------- flash attention v3: reg double-buffered K/V prefetch ----------------
// 4 waves x 32 q-rows (128 q/block), KVBLK=64, 32x32 MFMA, swapped QK^T,
// in-register softmax (T12 pack, T13 defer-max), T5 setprio, XCD swizzle.
struct Frags {
  bf16x8 kf[2][4];
  bf16x8 vf[2][4];
};

__device__ __forceinline__ void load_tile(Frags& F,
                                          const unsigned short* __restrict__ kb,
                                          const unsigned short* __restrict__ vb,
                                          int kv0, int qc, int hi) {
#pragma unroll
  for (int ks = 0; ks < 2; ++ks)
#pragma unroll
    for (int dc = 0; dc < 4; ++dc)
      F.kf[ks][dc] = *(const bf16x8*)&kb[(kv0 + ks * 32 + qc) * 64 + dc * 16 + 8 * hi];
#pragma unroll
  for (int dt = 0; dt < 2; ++dt)
#pragma unroll
    for (int c2 = 0; c2 < 4; ++c2)
      F.vf[dt][c2] = *(const bf16x8*)&vb[(dt * 32 + qc) * 2048 + kv0 + c2 * 16 + 8 * hi];
}

__device__ __forceinline__ void compute_tile(const Frags& F, const bf16x8 (&qf)[4],
                                             const float* __restrict__ smask,
                                             int kv0, int hi,
                                             f32x16 (&acco)[2], float& m_run, float& lrow) {
  const float kSc = 0.125f * UNITS;
  const float THR = 8.0f * UNITS;

  // ---- QK^T (swapped): S^T[k][q] ----
  f32x16 st0 = {}, st1 = {};
  __builtin_amdgcn_s_setprio(1);
#pragma unroll
  for (int dc = 0; dc < 4; ++dc) {
    st0 = __builtin_amdgcn_mfma_f32_32x32x16_bf16(F.kf[0][dc], qf[dc], st0, 0, 0, 0);
    st1 = __builtin_amdgcn_mfma_f32_32x32x16_bf16(F.kf[1][dc], qf[dc], st1, 0, 0, 0);
  }
  __builtin_amdgcn_s_setprio(0);

  float mf[2][16];
#pragma unroll
  for (int ks = 0; ks < 2; ++ks)
#pragma unroll
    for (int g = 0; g < 4; ++g) {
      float4 t = *(const float4*)&smask[kv0 + ks * 32 + 4 * hi + g * 8];
      mf[ks][g * 4 + 0] = t.x; mf[ks][g * 4 + 1] = t.y;
      mf[ks][g * 4 + 2] = t.z; mf[ks][g * 4 + 3] = t.w;
    }
  float p[2][16];
#pragma unroll
  for (int r = 0; r < 16; ++r) {
    p[0][r] = fmaf(st0[r], kSc, mf[0][r]);
    p[1][r] = fmaf(st1[r], kSc, mf[1][r]);
  }

  float a0 = p[0][0], a1 = p[0][1], a2 = p[0][2], a3 = p[0][3];
#pragma unroll
  for (int r = 4; r < 16; r += 4) {
    a0 = fmaxf(a0, p[0][r]); a1 = fmaxf(a1, p[0][r + 1]);
    a2 = fmaxf(a2, p[0][r + 2]); a3 = fmaxf(a3, p[0][r + 3]);
  }
#pragma unroll
  for (int r = 0; r < 16; r += 4) {
    a0 = fmaxf(a0, p[1][r]); a1 = fmaxf(a1, p[1][r + 1]);
    a2 = fmaxf(a2, p[1][r + 2]); a3 = fmaxf(a3, p[1][r + 3]);
  }
  float pm = fmaxf(fmaxf(a0, a1), fmaxf(a2, a3));
  pm = fmaxf(pm, __shfl_xor(pm, 32));

  if (!__all(pm <= m_run + THR)) {
    float mnew = fmaxf(m_run, pm);
    float scl = EXPF(m_run - mnew);
    lrow *= scl;
#pragma unroll
    for (int dt = 0; dt < 2; ++dt)
#pragma unroll
      for (int r = 0; r < 16; ++r) acco[dt][r] *= scl;
    m_run = mnew;
  }

  float s0 = 0.f, s1 = 0.f, s2 = 0.f, s3 = 0.f;
#pragma unroll
  for (int ks = 0; ks < 2; ++ks)
#pragma unroll
    for (int r = 0; r < 16; r += 4) {
      p[ks][r]     = EXPF(p[ks][r] - m_run);     s0 += p[ks][r];
      p[ks][r + 1] = EXPF(p[ks][r + 1] - m_run); s1 += p[ks][r + 1];
      p[ks][r + 2] = EXPF(p[ks][r + 2] - m_run); s2 += p[ks][r + 2];
      p[ks][r + 3] = EXPF(p[ks][r + 3] - m_run); s3 += p[ks][r + 3];
    }
  float ps = (s0 + s1) + (s2 + s3);
  ps += __shfl_xor(ps, 32);
  lrow += ps;

#pragma unroll
  for (int ks = 0; ks < 2; ++ks) {
    unsigned cp0 = pkbf(p[ks][0], p[ks][1]);
    unsigned cp1 = pkbf(p[ks][2], p[ks][3]);
    unsigned cp2 = pkbf(p[ks][4], p[ks][5]);
    unsigned cp3 = pkbf(p[ks][6], p[ks][7]);
    unsigned cp4 = pkbf(p[ks][8], p[ks][9]);
    unsigned cp5 = pkbf(p[ks][10], p[ks][11]);
    unsigned cp6 = pkbf(p[ks][12], p[ks][13]);
    unsigned cp7 = pkbf(p[ks][14], p[ks][15]);
    asm volatile("v_permlane32_swap_b32 %0, %1" : "+v"(cp0), "+v"(cp2));
    asm volatile("v_permlane32_swap_b32 %0, %1" : "+v"(cp1), "+v"(cp3));
    asm volatile("v_permlane32_swap_b32 %0, %1" : "+v"(cp4), "+v"(cp6));
    asm volatile("v_permlane32_swap_b32 %0, %1" : "+v"(cp5), "+v"(cp7));
    union { unsigned u[4]; bf16x8 v; } B0, B1;
    B0.u[0] = cp0; B0.u[1] = cp1; B0.u[2] = cp2; B0.u[3] = cp3;
    B1.u[0] = cp4; B1.u[1] = cp5; B1.u[2] = cp6; B1.u[3] = cp7;
    __builtin_amdgcn_s_setprio(1);
    acco[0] = __builtin_amdgcn_mfma_f32_32x32x16_bf16(F.vf[0][ks * 2 + 0], B0.v, acco[0], 0, 0, 0);
    acco[1] = __builtin_amdgcn_mfma_f32_32x32x16_bf16(F.vf[1][ks * 2 + 0], B0.v, acco[1], 0, 0, 0);
    acco[0] = __builtin_amdgcn_mfma_f32_32x32x16_bf16(F.vf[0][ks * 2 + 1], B1.v, acco[0], 0, 0, 0);
    acco[1] = __builtin_amdgcn_mfma_f32_32x32x16_bf16(F.vf[1][ks * 2 + 1], B1.v, acco[1], 0, 0, 0);
    __builtin_amdgcn_s_setprio(0);
  }
}

__global__ __launch_bounds__(256) void attn_kernel(const unsigned short* __restrict__ qh,
                                                   const unsigned short* __restrict__ kh,
                                                   const unsigned short* __restrict__ vt,
                                                   const float* __restrict__ mask,
                                                   float* __restrict__ out) {
  const int S = 2048;
  // XCD swizzle: HW maps block i -> XCD i%8; all 16 q-blocks of a bh share an XCD.
  int bid = blockIdx.x;
  int xcd = bid & 7, local = bid >> 3;
  int bh = xcd * 8 + (local & 7);
  int qblk = local >> 3;  // 0..15
  int b = bh >> 4, h = bh & 15;
  int tid = threadIdx.x, l = tid & 63, w = tid >> 6;
  int hi = l >> 5, qc = l & 31;

  const unsigned short* qb = qh + (long)bh * S * 64;
  const unsigned short* kb = kh + (long)bh * S * 64;
  const unsigned short* vb = vt + (long)bh * 64 * S;

  __shared__ float smask[2048];
  __shared__ float olds[4][16][65];
  for (int i = tid; i < S; i += 256)
    smask[i] = (-10000.0f * UNITS) * (1.0f - mask[b * S + i]);
  __syncthreads();

  const int q0 = qblk * 128 + w * 32;

  bf16x8 qf[4];
#pragma unroll
  for (int dc = 0; dc < 4; ++dc)
    qf[dc] = *(const bf16x8*)&qb[(q0 + qc) * 64 + dc * 16 + 8 * hi];

  f32x16 acco[2] = {};
  float m_run = -1e30f, lrow = 0.0f;

  Frags FA, FB;
  load_tile(FA, kb, vb, 0, qc, hi);

  for (int kv0 = 0; kv0 < S; kv0 += 128) {
    load_tile(FB, kb, vb, kv0 + 64, qc, hi);
    compute_tile(FA, qf, smask, kv0, hi, acco, m_run, lrow);
    int nxt = kv0 + 128;
    if (nxt >= S) nxt = 0;  // harmless reload of tile 0 on last iter
    load_tile(FA, kb, vb, nxt, qc, hi);
    compute_tile(FB, qf, smask, kv0 + 64, hi, acco, m_run, lrow);
  }

  // ---- epilogue: normalize, per-wave LDS transpose, coalesced fp32 stores ----
  float linv = 1.0f / lrow;
#pragma unroll
  for (int pass = 0; pass < 2; ++pass) {
    if ((qc >> 4) == pass) {
#pragma unroll
      for (int dt = 0; dt < 2; ++dt)
#pragma unroll
        for (int r = 0; r < 16; ++r) {
          int d = dt * 32 + (r & 3) + 8 * (r >> 2) + 4 * hi;
          olds[w][qc & 15][d] = acco[dt][r] * linv;
        }
    }
    asm volatile("s_waitcnt lgkmcnt(0)" ::: "memory");
#pragma unroll
    for (int r = 0; r < 16; ++r) {
      float val = olds[w][r][l];
      out[((long)b * 2048 + q0 + pass * 16 + r) * 1024 + h * 64 + l] = val;
    }
    asm volatile("s_waitcnt lgkmcnt(0)" ::: "memory");
  }
}

// ---------------- launch ----------------
extern "C" void kernel_launch(void* const* d_in, const int* in_sizes, int n_in,
                              void* d_out, int out_size, void* d_ws, size_t ws_size,
                              hipStream_t stream) {
  const float* q  = (const float*)d_in[0];
  const float* k  = (const float*)d_in[1];
  const float* v  = (const float*)d_in[2];
  const float* mask = (const float*)d_in[3];
  const float* wq = (const float*)d_in[4];
  const float* bq = (const float*)d_in[5];
  const float* wk = (const float*)d_in[6];
  const float* bk = (const float*)d_in[7];
  const float* wv = (const float*)d_in[8];
  const float* bv = (const float*)d_in[9];
  float* out = (float*)d_out;

  char* ws = (char*)d_ws;
  unsigned short* Xq = (unsigned short*)(ws);
  unsigned short* Xk = (unsigned short*)(ws + 16777216L);
  unsigned short* Xv = (unsigned short*)(ws + 33554432L);
  unsigned short* Wq = (unsigned short*)(ws + 50331648L);
  unsigned short* Wk = (unsigned short*)(ws + 52428800L);
  unsigned short* Wv = (unsigned short*)(ws + 54525952L);
  unsigned short* Qh = (unsigned short*)(ws + 56623104L);
  unsigned short* Kh = (unsigned short*)(ws + 73400320L);
  unsigned short* Vt = (unsigned short*)(ws + 90177536L);

  // 1) fused bf16 conversion (1 launch)
  conv_all<<<13824, 256, 0, stream>>>(q, k, v, wq, wk, wv, Xq, Xk, Xv, Wq, Wk, Wv);

  // 2) merged QKV projections (1 launch)
  dim3 ggrid(64, 8, 3);
  proj_gemm3<<<ggrid, 256, 0, stream>>>(Xq, Xk, Xv, Wq, Wk, Wv, bq, bk, bv, Qh, Kh, Vt);

  // 3) flash attention + head merge (1 launch)
  attn_kernel<<<1024, 256, 0, stream>>>(Qh, Kh, Vt, mask, out);
}

// Round 7
// 377.161 us; speedup vs baseline: 1.8968x; 1.2761x over previous
//
#include <hip/hip_runtime.h>
#include <hip/hip_bf16.h>
#include <stdint.h>

typedef __attribute__((ext_vector_type(4))) float f32x4;
typedef __attribute__((ext_vector_type(16))) float f32x16;
typedef __attribute__((ext_vector_type(8))) short bf16x8;

#define AS1 __attribute__((address_space(1)))
#define AS3 __attribute__((address_space(3)))

#if defined(__has_builtin)
#if __has_builtin(__builtin_amdgcn_exp2f)
#define EXPF(x) __builtin_amdgcn_exp2f(x)
#define UNITS 1.4426950408889634f
#endif
#endif
#ifndef EXPF
#define EXPF(x) __expf(x)
#define UNITS 1.0f
#endif

static __device__ __forceinline__ unsigned short f2bf(float f) {
  union { float f; unsigned u; } v; v.f = f;
  unsigned r = v.u + 0x7fffu + ((v.u >> 16) & 1u);
  return (unsigned short)(r >> 16);
}

static __device__ __forceinline__ unsigned pkbf(float lo, float hi) {
  __hip_bfloat162 h2 = __float22bfloat162_rn(make_float2(lo, hi));
  union { __hip_bfloat162 h; unsigned u; } c; c.h = h2; return c.u;
}

// ---------------- fused fp32 -> bf16 conversion for all 6 tensors ----------------
__global__ __launch_bounds__(256) void conv_all(
    const float* __restrict__ q, const float* __restrict__ k, const float* __restrict__ v,
    const float* __restrict__ wq, const float* __restrict__ wk, const float* __restrict__ wv,
    unsigned short* __restrict__ Xq, unsigned short* __restrict__ Xk, unsigned short* __restrict__ Xv,
    unsigned short* __restrict__ Wq, unsigned short* __restrict__ Wk, unsigned short* __restrict__ Wv) {
  int bid = blockIdx.x;
  const float* src; unsigned short* dst; int base;
  if (bid < 12288) {
    int t = bid >> 12;
    base = (bid & 4095) * 2048;
    if (t == 0) { src = q; dst = Xq; }
    else if (t == 1) { src = k; dst = Xk; }
    else { src = v; dst = Xv; }
  } else {
    int r = bid - 12288;
    int t = r >> 9;
    base = (r & 511) * 2048;
    if (t == 0) { src = wq; dst = Wq; }
    else if (t == 1) { src = wk; dst = Wk; }
    else { src = wv; dst = Wv; }
  }
  int i = base + threadIdx.x * 8;
  float4 x0 = *(const float4*)(src + i);
  float4 x1 = *(const float4*)(src + i + 4);
  ushort4 o0, o1;
  o0.x = f2bf(x0.x); o0.y = f2bf(x0.y); o0.z = f2bf(x0.z); o0.w = f2bf(x0.w);
  o1.x = f2bf(x1.x); o1.y = f2bf(x1.y); o1.z = f2bf(x1.z); o1.w = f2bf(x1.w);
  *(ushort4*)(dst + i) = o0;
  *(ushort4*)(dst + i + 4) = o1;
}

// ---------------- merged QKV projection GEMM (z selects q/k/v) ----------------
__global__ __launch_bounds__(256) void proj_gemm3(
    const unsigned short* __restrict__ Xq, const unsigned short* __restrict__ Xk,
    const unsigned short* __restrict__ Xv,
    const unsigned short* __restrict__ Wqp, const unsigned short* __restrict__ Wkp,
    const unsigned short* __restrict__ Wvp,
    const float* __restrict__ bq, const float* __restrict__ bk, const float* __restrict__ bv,
    unsigned short* __restrict__ Qh, unsigned short* __restrict__ Kh,
    unsigned short* __restrict__ Vt) {
  const int K = 1024, S = 2048, H = 16;
  int z = blockIdx.z;
  const unsigned short *A, *W; const float* bias; unsigned short* dst; int transpose_v;
  if (z == 0)      { A = Xq; W = Wqp; bias = bq; dst = Qh; transpose_v = 0; }
  else if (z == 1) { A = Xk; W = Wkp; bias = bk; dst = Kh; transpose_v = 0; }
  else             { A = Xv; W = Wvp; bias = bv; dst = Vt; transpose_v = 1; }

  __shared__ unsigned short As[128 * 32];
  __shared__ unsigned short Bs[128 * 32];
  const int tid = threadIdx.x;
  const int l = tid & 63;
  const int w = tid >> 6;
  const int m0 = blockIdx.x * 128, n0 = blockIdx.y * 128;
  const int wm = w >> 1, wn = w & 1;

  f32x4 acc[4][4] = {};

  const int srow = (l >> 2);
  const int skc = (l & 3) * 8;

  for (int k0 = 0; k0 < K; k0 += 32) {
#pragma unroll
    for (int i = 0; i < 2; ++i) {
      int slot = w * 2 + i;
      int row = slot * 16 + srow;
      const unsigned short* ga = A + (long)(m0 + row) * K + k0 + skc;
      const unsigned short* gb = W + (long)(n0 + row) * K + k0 + skc;
      __builtin_amdgcn_global_load_lds((const AS1 unsigned int*)ga,
                                       (AS3 unsigned int*)(As + slot * 512 + l * 8),
                                       16, 0, 0);
      __builtin_amdgcn_global_load_lds((const AS1 unsigned int*)gb,
                                       (AS3 unsigned int*)(Bs + slot * 512 + l * 8),
                                       16, 0, 0);
    }
    __syncthreads();

    bf16x8 af[4], bfr[4];
    const int kc = (l >> 4) * 8;
#pragma unroll
    for (int mi = 0; mi < 4; ++mi)
      af[mi] = *(const bf16x8*)&As[(wm * 64 + mi * 16 + (l & 15)) * 32 + kc];
#pragma unroll
    for (int ni = 0; ni < 4; ++ni)
      bfr[ni] = *(const bf16x8*)&Bs[(wn * 64 + ni * 16 + (l & 15)) * 32 + kc];
#pragma unroll
    for (int mi = 0; mi < 4; ++mi)
#pragma unroll
      for (int ni = 0; ni < 4; ++ni)
        acc[mi][ni] = __builtin_amdgcn_mfma_f32_16x16x32_bf16(af[mi], bfr[ni], acc[mi][ni], 0, 0, 0);
    __syncthreads();
  }

#pragma unroll
  for (int ni = 0; ni < 4; ++ni) {
    int col = n0 + wn * 64 + ni * 16 + (l & 15);
    float bv_ = bias[col];
    int h = col >> 6, dh = col & 63;
#pragma unroll
    for (int mi = 0; mi < 4; ++mi) {
#pragma unroll
      for (int r = 0; r < 4; ++r) {
        int m = m0 + wm * 64 + mi * 16 + (l >> 4) * 4 + r;
        int b = m >> 11, s = m & 2047;
        unsigned short obf = f2bf(acc[mi][ni][r] + bv_);
        long addr;
        if (!transpose_v)
          addr = ((long)(b * H + h) * S + s) * 64 + dh;
        else
          addr = ((long)(b * H + h) * 64 + dh) * S + s;
        dst[addr] = obf;
      }
    }
  }
}

// ---------------- flash attention v4: LDS-staged K/V, 2-phase async pipeline ----------------
// 8 waves x 32 q-rows (256 q/block), KVBLK=64, 32x32 MFMA, swapped QK^T,
// in-register softmax (T12/T13/T5). K/V staged via global_load_lds into a
// double-buffered LDS tile shared by all 8 waves; XOR-swizzled (T2, rule #21:
// inverse-swizzled global source + swizzled ds_read, linear LDS dest).
__device__ __forceinline__ void stage_tile(const unsigned short* __restrict__ kb,
                                           const unsigned short* __restrict__ vb,
                                           char* Kb, char* Vb, int kv0, int tid) {
  // thread t covers LDS bytes [t*16, t*16+16): tile row r=t>>3, swizzled slot s=(t&7)^(r&7)
  int r = tid >> 3;
  int s = (tid & 7) ^ (r & 7);
  const unsigned short* gk = kb + (kv0 + r) * 64 + s * 8;
  const unsigned short* gv = vb + r * 2048 + kv0 + s * 8;
  __builtin_amdgcn_global_load_lds((const AS1 unsigned int*)gk,
                                   (AS3 unsigned int*)(Kb + tid * 16), 16, 0, 0);
  __builtin_amdgcn_global_load_lds((const AS1 unsigned int*)gv,
                                   (AS3 unsigned int*)(Vb + tid * 16), 16, 0, 0);
}

__device__ __forceinline__ void compute_tile(const char* Kb, const char* Vb,
                                             const bf16x8 (&qf)[4],
                                             const float* __restrict__ smask,
                                             int kv0, int hi, int qc,
                                             f32x16 (&acco)[2], float& m_run, float& lrow) {
  const float kSc = 0.125f * UNITS;
  const float THR = 8.0f * UNITS;
  const int kx = qc & 7;

  // ---- fragments from swizzled LDS: addr = row*128 + ((slot)^(row&7))*16 ----
  bf16x8 kf[2][4], vf[2][4];
#pragma unroll
  for (int ks = 0; ks < 2; ++ks)
#pragma unroll
    for (int dc = 0; dc < 4; ++dc)
      kf[ks][dc] = *(const bf16x8*)(Kb + (ks * 32 + qc) * 128 + (((dc * 2 + hi) ^ kx) * 16));
#pragma unroll
  for (int dt = 0; dt < 2; ++dt)
#pragma unroll
    for (int c2 = 0; c2 < 4; ++c2)
      vf[dt][c2] = *(const bf16x8*)(Vb + (dt * 32 + qc) * 128 + (((c2 * 2 + hi) ^ kx) * 16));

  // ---- QK^T (swapped): S^T[k][q] ----
  f32x16 st0 = {}, st1 = {};
  __builtin_amdgcn_s_setprio(1);
#pragma unroll
  for (int dc = 0; dc < 4; ++dc) {
    st0 = __builtin_amdgcn_mfma_f32_32x32x16_bf16(kf[0][dc], qf[dc], st0, 0, 0, 0);
    st1 = __builtin_amdgcn_mfma_f32_32x32x16_bf16(kf[1][dc], qf[dc], st1, 0, 0, 0);
  }
  __builtin_amdgcn_s_setprio(0);

  float mf[2][16];
#pragma unroll
  for (int ks = 0; ks < 2; ++ks)
#pragma unroll
    for (int g = 0; g < 4; ++g) {
      float4 t = *(const float4*)&smask[kv0 + ks * 32 + 4 * hi + g * 8];
      mf[ks][g * 4 + 0] = t.x; mf[ks][g * 4 + 1] = t.y;
      mf[ks][g * 4 + 2] = t.z; mf[ks][g * 4 + 3] = t.w;
    }
  float p[2][16];
#pragma unroll
  for (int r = 0; r < 16; ++r) {
    p[0][r] = fmaf(st0[r], kSc, mf[0][r]);
    p[1][r] = fmaf(st1[r], kSc, mf[1][r]);
  }

  float a0 = p[0][0], a1 = p[0][1], a2 = p[0][2], a3 = p[0][3];
#pragma unroll
  for (int r = 4; r < 16; r += 4) {
    a0 = fmaxf(a0, p[0][r]); a1 = fmaxf(a1, p[0][r + 1]);
    a2 = fmaxf(a2, p[0][r + 2]); a3 = fmaxf(a3, p[0][r + 3]);
  }
#pragma unroll
  for (int r = 0; r < 16; r += 4) {
    a0 = fmaxf(a0, p[1][r]); a1 = fmaxf(a1, p[1][r + 1]);
    a2 = fmaxf(a2, p[1][r + 2]); a3 = fmaxf(a3, p[1][r + 3]);
  }
  float pm = fmaxf(fmaxf(a0, a1), fmaxf(a2, a3));
  pm = fmaxf(pm, __shfl_xor(pm, 32));

  if (!__all(pm <= m_run + THR)) {
    float mnew = fmaxf(m_run, pm);
    float scl = EXPF(m_run - mnew);
    lrow *= scl;
#pragma unroll
    for (int dt = 0; dt < 2; ++dt)
#pragma unroll
      for (int r = 0; r < 16; ++r) acco[dt][r] *= scl;
    m_run = mnew;
  }

  float s0 = 0.f, s1 = 0.f, s2 = 0.f, s3 = 0.f;
#pragma unroll
  for (int ks = 0; ks < 2; ++ks)
#pragma unroll
    for (int r = 0; r < 16; r += 4) {
      p[ks][r]     = EXPF(p[ks][r] - m_run);     s0 += p[ks][r];
      p[ks][r + 1] = EXPF(p[ks][r + 1] - m_run); s1 += p[ks][r + 1];
      p[ks][r + 2] = EXPF(p[ks][r + 2] - m_run); s2 += p[ks][r + 2];
      p[ks][r + 3] = EXPF(p[ks][r + 3] - m_run); s3 += p[ks][r + 3];
    }
  float ps = (s0 + s1) + (s2 + s3);
  ps += __shfl_xor(ps, 32);
  lrow += ps;

#pragma unroll
  for (int ks = 0; ks < 2; ++ks) {
    unsigned cp0 = pkbf(p[ks][0], p[ks][1]);
    unsigned cp1 = pkbf(p[ks][2], p[ks][3]);
    unsigned cp2 = pkbf(p[ks][4], p[ks][5]);
    unsigned cp3 = pkbf(p[ks][6], p[ks][7]);
    unsigned cp4 = pkbf(p[ks][8], p[ks][9]);
    unsigned cp5 = pkbf(p[ks][10], p[ks][11]);
    unsigned cp6 = pkbf(p[ks][12], p[ks][13]);
    unsigned cp7 = pkbf(p[ks][14], p[ks][15]);
    asm volatile("v_permlane32_swap_b32 %0, %1" : "+v"(cp0), "+v"(cp2));
    asm volatile("v_permlane32_swap_b32 %0, %1" : "+v"(cp1), "+v"(cp3));
    asm volatile("v_permlane32_swap_b32 %0, %1" : "+v"(cp4), "+v"(cp6));
    asm volatile("v_permlane32_swap_b32 %0, %1" : "+v"(cp5), "+v"(cp7));
    union { unsigned u[4]; bf16x8 v; } B0, B1;
    B0.u[0] = cp0; B0.u[1] = cp1; B0.u[2] = cp2; B0.u[3] = cp3;
    B1.u[0] = cp4; B1.u[1] = cp5; B1.u[2] = cp6; B1.u[3] = cp7;
    __builtin_amdgcn_s_setprio(1);
    acco[0] = __builtin_amdgcn_mfma_f32_32x32x16_bf16(vf[0][ks * 2 + 0], B0.v, acco[0], 0, 0, 0);
    acco[1] = __builtin_amdgcn_mfma_f32_32x32x16_bf16(vf[1][ks * 2 + 0], B0.v, acco[1], 0, 0, 0);
    acco[0] = __builtin_amdgcn_mfma_f32_32x32x16_bf16(vf[0][ks * 2 + 1], B1.v, acco[0], 0, 0, 0);
    acco[1] = __builtin_amdgcn_mfma_f32_32x32x16_bf16(vf[1][ks * 2 + 1], B1.v, acco[1], 0, 0, 0);
    __builtin_amdgcn_s_setprio(0);
  }
}

__global__ __launch_bounds__(512, 2) void attn_kernel(const unsigned short* __restrict__ qh,
                                                      const unsigned short* __restrict__ kh,
                                                      const unsigned short* __restrict__ vt,
                                                      const float* __restrict__ mask,
                                                      float* __restrict__ out) {
  const int S = 2048;
  // XCD swizzle: HW maps block i -> XCD i%8; all 8 q-blocks of a bh share an XCD.
  int bid = blockIdx.x;
  int xcd = bid & 7, jj = bid >> 3;
  int bh = xcd * 8 + (jj & 7);
  int qblk = jj >> 3;  // 0..7
  int b = bh >> 4, h = bh & 15;
  int tid = threadIdx.x, l = tid & 63, w = tid >> 6;
  int hi = l >> 5, qc = l & 31;

  const unsigned short* qb = qh + (long)bh * S * 64;
  const unsigned short* kb = kh + (long)bh * S * 64;
  const unsigned short* vb = vt + (long)bh * 64 * S;

  __shared__ float smask[2048];
  // pool: [2][ K(8KB) + V(8KB) ] double buffer = 32 KB; reused as olds[8][16][65] (33280 B)
  __shared__ __align__(16) char pool[33280];
  for (int i = tid; i < S; i += 512)
    smask[i] = (-10000.0f * UNITS) * (1.0f - mask[b * S + i]);
  __syncthreads();

  const int q0 = qblk * 256 + w * 32;

  bf16x8 qf[4];
#pragma unroll
  for (int dc = 0; dc < 4; ++dc)
    qf[dc] = *(const bf16x8*)&qb[(q0 + qc) * 64 + dc * 16 + 8 * hi];

  f32x16 acco[2] = {};
  float m_run = -1e30f, lrow = 0.0f;

  // 2-phase pipeline: stage(next) issued before compute(cur); __syncthreads
  // (vmcnt(0)+lgkmcnt(0)+barrier) at tile end — latency hidden under compute.
  stage_tile(kb, vb, pool, pool + 8192, 0, tid);
  __syncthreads();

  for (int t = 0; t < 32; ++t) {
    char* cur = pool + (t & 1) * 16384;
    if (t < 31) {
      char* nxt = pool + ((t + 1) & 1) * 16384;
      stage_tile(kb, vb, nxt, nxt + 8192, (t + 1) * 64, tid);
    }
    compute_tile(cur, cur + 8192, qf, smask, t * 64, hi, qc, acco, m_run, lrow);
    __syncthreads();
  }

  // ---- epilogue: normalize, per-wave LDS transpose (pool reused), coalesced stores ----
  float (*olds)[16][65] = (float (*)[16][65])pool;
  float linv = 1.0f / lrow;
#pragma unroll
  for (int pass = 0; pass < 2; ++pass) {
    if ((qc >> 4) == pass) {
#pragma unroll
      for (int dt = 0; dt < 2; ++dt)
#pragma unroll
        for (int r = 0; r < 16; ++r) {
          int d = dt * 32 + (r & 3) + 8 * (r >> 2) + 4 * hi;
          olds[w][qc & 15][d] = acco[dt][r] * linv;
        }
    }
    asm volatile("s_waitcnt lgkmcnt(0)" ::: "memory");
#pragma unroll
    for (int r = 0; r < 16; ++r) {
      float val = olds[w][r][l];
      out[((long)b * 2048 + q0 + pass * 16 + r) * 1024 + h * 64 + l] = val;
    }
    asm volatile("s_waitcnt lgkmcnt(0)" ::: "memory");
  }
}

// ---------------- launch ----------------
extern "C" void kernel_launch(void* const* d_in, const int* in_sizes, int n_in,
                              void* d_out, int out_size, void* d_ws, size_t ws_size,
                              hipStream_t stream) {
  const float* q  = (const float*)d_in[0];
  const float* k  = (const float*)d_in[1];
  const float* v  = (const float*)d_in[2];
  const float* mask = (const float*)d_in[3];
  const float* wq = (const float*)d_in[4];
  const float* bq = (const float*)d_in[5];
  const float* wk = (const float*)d_in[6];
  const float* bk = (const float*)d_in[7];
  const float* wv = (const float*)d_in[8];
  const float* bv = (const float*)d_in[9];
  float* out = (float*)d_out;

  char* ws = (char*)d_ws;
  unsigned short* Xq = (unsigned short*)(ws);
  unsigned short* Xk = (unsigned short*)(ws + 16777216L);
  unsigned short* Xv = (unsigned short*)(ws + 33554432L);
  unsigned short* Wq = (unsigned short*)(ws + 50331648L);
  unsigned short* Wk = (unsigned short*)(ws + 52428800L);
  unsigned short* Wv = (unsigned short*)(ws + 54525952L);
  unsigned short* Qh = (unsigned short*)(ws + 56623104L);
  unsigned short* Kh = (unsigned short*)(ws + 73400320L);
  unsigned short* Vt = (unsigned short*)(ws + 90177536L);

  // 1) fused bf16 conversion (1 launch)
  conv_all<<<13824, 256, 0, stream>>>(q, k, v, wq, wk, wv, Xq, Xk, Xv, Wq, Wk, Wv);

  // 2) merged QKV projections (1 launch)
  dim3 ggrid(64, 8, 3);
  proj_gemm3<<<ggrid, 256, 0, stream>>>(Xq, Xk, Xv, Wq, Wk, Wv, bq, bk, bv, Qh, Kh, Vt);

  // 3) flash attention + head merge (1 launch)
  attn_kernel<<<512, 512, 0, stream>>>(Qh, Kh, Vt, mask, out);
}